// Round 9
// baseline (473.242 us; speedup 1.0000x reference)
//
#include <hip/hip_runtime.h>
#include <math.h>

#define L 2048
#define DMODEL 512
#define NH 8
#define DH 64
#define NROWS 4096   // B*L

typedef __attribute__((ext_vector_type(4))) float f32x4;
typedef __attribute__((ext_vector_type(8))) short s16x8;

#define MFMA(a, b, c) __builtin_amdgcn_mfma_f32_16x16x32_bf16(a, b, c, 0, 0, 0)

static __device__ __forceinline__ ushort f2b(float f) {
    union { float f; unsigned u; } v; v.f = f;
    unsigned r = v.u + 0x7FFF + ((v.u >> 16) & 1);
    return (ushort)(r >> 16);
}

// ---------- f32 -> bf16 convert (8 elems/thread) ----------
__global__ __launch_bounds__(256)
void cvt_bf16(const float* __restrict__ in, ushort* __restrict__ out, int n8) {
    int i = blockIdx.x * 256 + threadIdx.x;
    if (i < n8) {
        float4 a = *reinterpret_cast<const float4*>(&in[(size_t)i * 8]);
        float4 b = *reinterpret_cast<const float4*>(&in[(size_t)i * 8 + 4]);
        ushort4 o0; o0.x = f2b(a.x); o0.y = f2b(a.y); o0.z = f2b(a.z); o0.w = f2b(a.w);
        ushort4 o1; o1.x = f2b(b.x); o1.y = f2b(b.y); o1.z = f2b(b.z); o1.w = f2b(b.w);
        *reinterpret_cast<ushort4*>(&out[(size_t)i * 8]) = o0;
        *reinterpret_cast<ushort4*>(&out[(size_t)i * 8 + 4]) = o1;
    }
}

// ---------- zero the l-accumulator ----------
__global__ __launch_bounds__(256)
void zerol(float* __restrict__ lg) {
    lg[blockIdx.x * 256 + threadIdx.x] = 0.0f;
}

// ---------- W (512x512 f32, row-major [k][n]) -> Wt bf16 [n][k] ----------
__global__ __launch_bounds__(256)
void transpose_w(const float* __restrict__ W0, const float* __restrict__ W1,
                 const float* __restrict__ W2, const float* __restrict__ W3,
                 ushort* __restrict__ T0, ushort* __restrict__ T1,
                 ushort* __restrict__ T2, ushort* __restrict__ T3) {
    const int z = blockIdx.z;
    const float* W = z == 0 ? W0 : (z == 1 ? W1 : (z == 2 ? W2 : W3));
    ushort* T = z == 0 ? T0 : (z == 1 ? T1 : (z == 2 ? T2 : T3));
    __shared__ float Ls[64][65];
    const int tid = threadIdx.x;
    const int k0 = blockIdx.y * 64, n0 = blockIdx.x * 64;
    #pragma unroll
    for (int i = 0; i < 4; ++i) {
        int kk = (tid >> 4) + i * 16, n4 = (tid & 15) * 4;
        float4 v = *reinterpret_cast<const float4*>(&W[(size_t)(k0 + kk) * 512 + n0 + n4]);
        Ls[kk][n4] = v.x; Ls[kk][n4 + 1] = v.y; Ls[kk][n4 + 2] = v.z; Ls[kk][n4 + 3] = v.w;
    }
    __syncthreads();
    #pragma unroll
    for (int i = 0; i < 4; ++i) {
        int nn = (tid >> 4) + i * 16, k4 = (tid & 15) * 4;
        ushort4 o;
        o.x = f2b(Ls[k4 + 0][nn]); o.y = f2b(Ls[k4 + 1][nn]);
        o.z = f2b(Ls[k4 + 2][nn]); o.w = f2b(Ls[k4 + 3][nn]);
        *reinterpret_cast<ushort4*>(&T[(size_t)(n0 + nn) * 512 + k0 + k4]) = o;
    }
}

// ---------- bf16 MFMA GEMM: out = A(4096x512) @ Wt^T + bias ----------
// a_f32: 0 = bf16 A; 1 = f32 A (convert in staging);
//        2 = A = (og0 + og1) * (1/lg[row,head]) f32->bf16 (out-projection).
// per-z mode nibble: 0: f32 row-major; 1: bf16 (B,H,L,DH); 2: bf16 (B,H,DH,L).
__global__ __launch_bounds__(256)
void gemm_bf16(const void* __restrict__ A0, const void* __restrict__ A1,
               const void* __restrict__ A2,
               const ushort* __restrict__ W0, const ushort* __restrict__ W1,
               const ushort* __restrict__ W2,
               const float* __restrict__ b0, const float* __restrict__ b1,
               const float* __restrict__ b2,
               void* o0, void* o1, void* o2,
               const float* __restrict__ ogB, const float* __restrict__ lgp,
               int a_f32, int modes) {
    const int z = blockIdx.z;
    const void* A   = z == 0 ? A0 : (z == 1 ? A1 : A2);
    const ushort* Wt = z == 0 ? W0 : (z == 1 ? W1 : W2);
    const float* bias = z == 0 ? b0 : (z == 1 ? b1 : b2);
    void* outp = z == 0 ? o0 : (z == 1 ? o1 : o2);
    const int mode = (modes >> (4 * z)) & 15;

    __shared__ ushort As[128][40];
    __shared__ ushort Bs[64][40];
    const int tid = threadIdx.x;
    const int w = tid >> 6, lane = tid & 63, g = lane >> 4, c = lane & 15;
    const int m0 = blockIdx.y * 128, n0 = blockIdx.x * 64;

    f32x4 acc[2][4];
    #pragma unroll
    for (int rs = 0; rs < 2; ++rs)
        #pragma unroll
        for (int cs = 0; cs < 4; ++cs) acc[rs][cs] = (f32x4){0.f, 0.f, 0.f, 0.f};

    float bsv[4];
    #pragma unroll
    for (int cs = 0; cs < 4; ++cs) bsv[cs] = bias[n0 + 16 * cs + c];

    for (int k0 = 0; k0 < 512; k0 += 32) {
        {
            int row = tid >> 1, kh = (tid & 1) * 16;
            if (a_f32 == 1) {
                const float* p = (const float*)A + (size_t)(m0 + row) * 512 + k0 + kh;
                ushort tmp[16];
                #pragma unroll
                for (int q4 = 0; q4 < 4; ++q4) {
                    float4 f = *reinterpret_cast<const float4*>(p + q4 * 4);
                    tmp[q4 * 4 + 0] = f2b(f.x); tmp[q4 * 4 + 1] = f2b(f.y);
                    tmp[q4 * 4 + 2] = f2b(f.z); tmp[q4 * 4 + 3] = f2b(f.w);
                }
                *reinterpret_cast<uint4*>(&As[row][kh]) = *reinterpret_cast<uint4*>(&tmp[0]);
                *reinterpret_cast<uint4*>(&As[row][kh + 8]) = *reinterpret_cast<uint4*>(&tmp[8]);
            } else if (a_f32 == 2) {
                const size_t idx = (size_t)(m0 + row) * 512 + k0 + kh;
                const float* p0 = (const float*)A + idx;
                const float* p1 = ogB + idx;
                const int bb = (m0 + row) >> 11, l = (m0 + row) & 2047;
                const int head = (k0 + kh) >> 6;
                const float inv = 1.0f / lgp[(((size_t)bb * NH + head) << 11) + l];
                ushort tmp[16];
                #pragma unroll
                for (int q4 = 0; q4 < 4; ++q4) {
                    float4 f = *reinterpret_cast<const float4*>(p0 + q4 * 4);
                    float4 f1 = *reinterpret_cast<const float4*>(p1 + q4 * 4);
                    tmp[q4 * 4 + 0] = f2b((f.x + f1.x) * inv);
                    tmp[q4 * 4 + 1] = f2b((f.y + f1.y) * inv);
                    tmp[q4 * 4 + 2] = f2b((f.z + f1.z) * inv);
                    tmp[q4 * 4 + 3] = f2b((f.w + f1.w) * inv);
                }
                *reinterpret_cast<uint4*>(&As[row][kh]) = *reinterpret_cast<uint4*>(&tmp[0]);
                *reinterpret_cast<uint4*>(&As[row][kh + 8]) = *reinterpret_cast<uint4*>(&tmp[8]);
            } else {
                const ushort* p = (const ushort*)A + (size_t)(m0 + row) * 512 + k0 + kh;
                uint4 x0 = *reinterpret_cast<const uint4*>(p);
                uint4 x1 = *reinterpret_cast<const uint4*>(p + 8);
                *reinterpret_cast<uint4*>(&As[row][kh]) = x0;
                *reinterpret_cast<uint4*>(&As[row][kh + 8]) = x1;
            }
        }
        {
            int n = tid >> 2, kh = (tid & 3) * 8;
            uint4 x = *reinterpret_cast<const uint4*>(&Wt[(size_t)(n0 + n) * 512 + k0 + kh]);
            *reinterpret_cast<uint4*>(&Bs[n][kh]) = x;
        }
        __syncthreads();
        s16x8 af[2], bf[4];
        #pragma unroll
        for (int rs = 0; rs < 2; ++rs)
            af[rs] = *reinterpret_cast<const s16x8*>(&As[32 * w + 16 * rs + c][8 * g]);
        #pragma unroll
        for (int cs = 0; cs < 4; ++cs)
            bf[cs] = *reinterpret_cast<const s16x8*>(&Bs[16 * cs + c][8 * g]);
        #pragma unroll
        for (int rs = 0; rs < 2; ++rs)
            #pragma unroll
            for (int cs = 0; cs < 4; ++cs)
                acc[rs][cs] = MFMA(af[rs], bf[cs], acc[rs][cs]);
        __syncthreads();
    }
    #pragma unroll
    for (int rs = 0; rs < 2; ++rs)
        #pragma unroll
        for (int cs = 0; cs < 4; ++cs)
            #pragma unroll
            for (int r = 0; r < 4; ++r) {
                int row = m0 + 32 * w + 16 * rs + 4 * g + r;
                int n = n0 + 16 * cs + c;
                float v = acc[rs][cs][r] + bsv[cs];
                int bb = row >> 11, l = row & 2047, hh = n >> 6, dh = n & 63;
                if (mode == 0) {
                    ((float*)outp)[(size_t)row * 512 + n] = v;
                } else if (mode == 1) {
                    ((ushort*)outp)[(((size_t)bb * NH + hh) * L + l) * DH + dh] = f2b(v);
                } else {
                    ((ushort*)outp)[(((size_t)bb * NH + hh) * DH + dh) * L + l] = f2b(v);
                }
            }
}

// ---------- fused relative attention ----------
// Grid 2048: ib = 63-(bid>>5) (heavy-first), bh = (bid>>1)&15, half = bid&1.
// Each block computes its half of the i-block's key tiles; waves own
// CONSECUTIVE tile sub-ranges so the E-window T-strip is half-reused
// (8 new T MFMAs per tile instead of 16).  Writes unnormalized p = exp(s)
// f32 straight to attnw (no LDS staging, no barrier in the main loop),
// partial l via one atomicAdd per row, partial O to og[half] (f32).
__global__ __launch_bounds__(256, 6)
void attn(const ushort* __restrict__ qws, const ushort* __restrict__ kws,
          const ushort* __restrict__ vtg, const ushort* __restrict__ Ebf,
          float* __restrict__ attnw, float* __restrict__ og0,
          float* __restrict__ og1, float* __restrict__ lg) {
    __shared__ ushort PwAll[4][32 * 40];    // per-wave P scratch (bf16)
    __shared__ float Obuf[32][68];
    __shared__ float lred[4][32];

    const int tid = threadIdx.x;
    const int w = tid >> 6, lane = tid & 63, g = lane >> 4, c = lane & 15;
    const int bid = blockIdx.x;
    const int ib = 63 - (bid >> 5);
    const int bh = (bid >> 1) & 15;
    const int half = bid & 1;
    const int b = bh >> 3, h = bh & 7;
    const int i0 = ib * 32;
    const int nt = ib + 1;
    const int mid = (nt + 1) >> 1;
    const int h0 = half ? mid : 0;
    const int h1 = half ? nt : mid;
    const int len = h1 - h0;
    const int tw0 = h0 + ((len * w) >> 2);
    const int tw1 = h0 + ((len * (w + 1)) >> 2);

    const ushort* qb = qws + (size_t)bh * L * DH;
    const ushort* kb = kws + (size_t)bh * L * DH;
    const ushort* vt = vtg + (size_t)bh * DH * L;
    float* ab = attnw + (size_t)bh * L * L;
    float* og = half ? og1 : og0;

    ushort* Pw = &PwAll[w][0];              // [32][40] bf16

    s16x8 aq[2][2];
    #pragma unroll
    for (int rs = 0; rs < 2; ++rs)
        #pragma unroll
        for (int ks = 0; ks < 2; ++ks)
            aq[rs][ks] = *reinterpret_cast<const s16x8*>(
                qb + (size_t)(i0 + 16 * rs + c) * DH + 32 * ks + 8 * g);

    float lsum[2][4] = {};
    f32x4 O[2][4];
    #pragma unroll
    for (int rs = 0; rs < 2; ++rs)
        #pragma unroll
        for (int cs = 0; cs < 4; ++cs) O[rs][cs] = (f32x4){0.f, 0.f, 0.f, 0.f};

    f32x4 TT[4][2];
    if (tw0 < tw1) {
        // initial T for window cols [0,32) of tile tw0
        const int rbase = L - 32 - i0 + tw0 * 32;
        #pragma unroll
        for (int ct = 0; ct < 2; ++ct) {
            int rg = rbase + 16 * ct + c;
            rg = rg > L - 1 ? L - 1 : rg;
            s16x8 be0 = *reinterpret_cast<const s16x8*>(Ebf + (size_t)rg * DH + 8 * g);
            s16x8 be1 = *reinterpret_cast<const s16x8*>(Ebf + (size_t)rg * DH + 32 + 8 * g);
            #pragma unroll
            for (int rs = 0; rs < 2; ++rs) {
                f32x4 x = {0.f, 0.f, 0.f, 0.f};
                x = MFMA(aq[rs][0], be0, x);
                x = MFMA(aq[rs][1], be1, x);
                TT[ct][rs] = x;
            }
        }
    }

    for (int t = tw0; t < tw1; ++t) {
        const int j0 = t * 32;
        const int rbase = L - 32 - i0 + j0;
        // --- new T half: window cols [32,64) ---
        #pragma unroll
        for (int ct = 0; ct < 2; ++ct) {
            int rg = rbase + 32 + 16 * ct + c;
            rg = rg > L - 1 ? L - 1 : rg;   // clamped rows feed masked cols only
            s16x8 be0 = *reinterpret_cast<const s16x8*>(Ebf + (size_t)rg * DH + 8 * g);
            s16x8 be1 = *reinterpret_cast<const s16x8*>(Ebf + (size_t)rg * DH + 32 + 8 * g);
            #pragma unroll
            for (int rs = 0; rs < 2; ++rs) {
                f32x4 x = {0.f, 0.f, 0.f, 0.f};
                x = MFMA(aq[rs][0], be0, x);
                x = MFMA(aq[rs][1], be1, x);
                TT[2 + ct][rs] = x;
            }
        }
        // --- in-wave diagonal gather: rel = T[il][31+jl-il] ---
        float rel[2][2][4];
        #pragma unroll
        for (int r = 0; r < 4; ++r) {
            const int u = c - 4 * g - r;
            const int src = (lane & 48) | ((15 + u) & 15);
            const bool hi = (u >= 1);
            #pragma unroll
            for (int rs = 0; rs < 2; ++rs)
                #pragma unroll
                for (int jh = 0; jh < 2; ++jh) {
                    const int b0 = jh - rs + 1;
                    float va = __shfl(TT[b0][rs][r], src);
                    float vb = __shfl(TT[b0 + 1][rs][r], src);
                    rel[rs][jh][r] = hi ? vb : va;
                }
        }
        // --- QK^T, p = exp(s), l accum, direct p store + Pw stage ---
        s16x8 bk[2][2];
        #pragma unroll
        for (int jh = 0; jh < 2; ++jh)
            #pragma unroll
            for (int ks = 0; ks < 2; ++ks)
                bk[jh][ks] = *reinterpret_cast<const s16x8*>(
                    kb + (size_t)(j0 + 16 * jh + c) * DH + 32 * ks + 8 * g);
        float* prow = ab + (size_t)i0 * L + j0;
        #pragma unroll
        for (int rs = 0; rs < 2; ++rs)
            #pragma unroll
            for (int jh = 0; jh < 2; ++jh) {
                f32x4 x = {0.f, 0.f, 0.f, 0.f};
                x = MFMA(aq[rs][0], bk[jh][0], x);
                x = MFMA(aq[rs][1], bk[jh][1], x);
                #pragma unroll
                for (int r = 0; r < 4; ++r) {
                    const int il = 16 * rs + 4 * g + r;
                    const int jl = 16 * jh + c;
                    float s = (x[r] + rel[rs][jh][r]) * 0.125f;
                    float p = (j0 + jl <= i0 + il) ? __expf(s) : 0.0f;
                    lsum[rs][r] += p;
                    prow[(size_t)il * L + jl] = p;
                    Pw[il * 40 + jl] = f2b(p);
                }
            }
        // --- PV with unnormalized bf16 P ---
        s16x8 pa[2];
        #pragma unroll
        for (int rs2 = 0; rs2 < 2; ++rs2)
            pa[rs2] = *reinterpret_cast<const s16x8*>(&Pw[(16 * rs2 + c) * 40 + 8 * g]);
        #pragma unroll
        for (int cs = 0; cs < 4; ++cs) {
            s16x8 vtb = *reinterpret_cast<const s16x8*>(
                vt + (size_t)(16 * cs + c) * L + j0 + 8 * g);
            #pragma unroll
            for (int rs2 = 0; rs2 < 2; ++rs2)
                O[rs2][cs] = MFMA(pa[rs2], vtb, O[rs2][cs]);
        }
        // --- shift T window ---
        #pragma unroll
        for (int rs = 0; rs < 2; ++rs) {
            TT[0][rs] = TT[2][rs];
            TT[1][rs] = TT[3][rs];
        }
    }

    // --- l partial: lane merge then one atomicAdd per row ---
    #pragma unroll
    for (int rs = 0; rs < 2; ++rs)
        #pragma unroll
        for (int r = 0; r < 4; ++r) {
            float s = lsum[rs][r];
            s += __shfl_xor(s, 1); s += __shfl_xor(s, 2);
            s += __shfl_xor(s, 4); s += __shfl_xor(s, 8);
            if (c == 0) lred[w][16 * rs + 4 * g + r] = s;
        }
    __syncthreads();
    if (tid < 32)
        atomicAdd(&lg[((size_t)bh << 11) + i0 + tid],
                  lred[0][tid] + lred[1][tid] + lred[2][tid] + lred[3][tid]);

    // --- O merge across waves (wave-sequential into Obuf) ---
    #pragma unroll
    for (int ww = 0; ww < 4; ++ww) {
        if (w == ww) {
            #pragma unroll
            for (int rs2 = 0; rs2 < 2; ++rs2)
                #pragma unroll
                for (int cs = 0; cs < 4; ++cs)
                    #pragma unroll
                    for (int r = 0; r < 4; ++r) {
                        const int row = 16 * rs2 + 4 * g + r;
                        const int col = 16 * cs + c;
                        if (ww == 0) Obuf[row][col] = O[rs2][cs][r];
                        else         Obuf[row][col] += O[rs2][cs][r];
                    }
        }
        __syncthreads();
    }
    {   // write partial O (f32, unnormalized) to og[half], (B,L,D) layout
        const int i = tid >> 3, d8 = (tid & 7) * 8;
        float* dst = &og[((size_t)b * L + i0 + i) * DMODEL + h * DH + d8];
        *reinterpret_cast<float4*>(dst) = *reinterpret_cast<const float4*>(&Obuf[i][d8]);
        *reinterpret_cast<float4*>(dst + 4) = *reinterpret_cast<const float4*>(&Obuf[i][d8 + 4]);
    }
}

// ---------- in-place row rescale of attnw + masked-region zero fill ----------
__global__ __launch_bounds__(256)
void rescale(float* __restrict__ attnw, const float* __restrict__ lg) {
    const int blk = blockIdx.x;
    const int bh = blk >> 11, i = blk & 2047;
    const float inv = 1.0f / lg[((size_t)bh << 11) + i];
    float* rowp = attnw + (((size_t)bh << 11) + i) * 2048;
    const int col0 = threadIdx.x * 8;
    float4 a, b2;
    if (col0 + 7 <= i) {
        a  = *reinterpret_cast<const float4*>(rowp + col0);
        b2 = *reinterpret_cast<const float4*>(rowp + col0 + 4);
        a.x *= inv; a.y *= inv; a.z *= inv; a.w *= inv;
        b2.x *= inv; b2.y *= inv; b2.z *= inv; b2.w *= inv;
    } else if (col0 <= i) {
        a  = *reinterpret_cast<const float4*>(rowp + col0);
        b2 = *reinterpret_cast<const float4*>(rowp + col0 + 4);
        a.x  = (col0 + 0 <= i) ? a.x  * inv : 0.f;
        a.y  = (col0 + 1 <= i) ? a.y  * inv : 0.f;
        a.z  = (col0 + 2 <= i) ? a.z  * inv : 0.f;
        a.w  = (col0 + 3 <= i) ? a.w  * inv : 0.f;
        b2.x = (col0 + 4 <= i) ? b2.x * inv : 0.f;
        b2.y = (col0 + 5 <= i) ? b2.y * inv : 0.f;
        b2.z = (col0 + 6 <= i) ? b2.z * inv : 0.f;
        b2.w = (col0 + 7 <= i) ? b2.w * inv : 0.f;
    } else {
        a = make_float4(0.f, 0.f, 0.f, 0.f);
        b2 = a;
    }
    *reinterpret_cast<float4*>(rowp + col0) = a;
    *reinterpret_cast<float4*>(rowp + col0 + 4) = b2;
}

extern "C" void kernel_launch(void* const* d_in, const int* in_sizes, int n_in,
                              void* d_out, int out_size, void* d_ws, size_t ws_size,
                              hipStream_t stream) {
    const float* q_in = (const float*)d_in[0];
    const float* k_in = (const float*)d_in[1];
    const float* v_in = (const float*)d_in[2];
    const float* Wq  = (const float*)d_in[4];
    const float* bq  = (const float*)d_in[5];
    const float* Wk  = (const float*)d_in[6];
    const float* bk  = (const float*)d_in[7];
    const float* Wv  = (const float*)d_in[8];
    const float* bv  = (const float*)d_in[9];
    const float* Wfc = (const float*)d_in[10];
    const float* bfc = (const float*)d_in[11];
    const float* E   = (const float*)d_in[12];

    float* out0  = (float*)d_out;                        // (B,L,D) f32
    float* attnw = out0 + (size_t)2 * L * DMODEL;        // (B,H,L,L) f32

    const size_t NA = (size_t)NROWS * DMODEL;            // 2,097,152
    ushort* ws = (ushort*)d_ws;
    ushort* Ebf  = ws;                                   // 131072 us
    ushort* Wqt  = Ebf + (size_t)L * DH;
    ushort* Wkt  = Wqt + 262144;
    ushort* Wvt  = Wkt + 262144;
    ushort* Wfct = Wvt + 262144;
    ushort* qws  = Wfct + 262144;
    ushort* kws  = qws + NA;
    ushort* vtg  = kws + NA;                             // (B,H,DH,L) bf16
    float*  og0  = (float*)(vtg + NA);                   // (B,L,D) f32
    float*  og1  = og0 + NA;                             // (B,L,D) f32
    float*  lg   = og1 + NA;                             // (B*H, L) f32

    cvt_bf16<<<dim3(64), 256, 0, stream>>>(E, Ebf, (int)(L * DH / 8));
    transpose_w<<<dim3(8, 8, 4), 256, 0, stream>>>(Wq, Wk, Wv, Wfc, Wqt, Wkt, Wvt, Wfct);
    zerol<<<dim3(128), 256, 0, stream>>>(lg);
    // q, k -> (B,H,L,DH); v -> transposed (B,H,DH,L)
    gemm_bf16<<<dim3(8, 32, 3), 256, 0, stream>>>(q_in, k_in, v_in, Wqt, Wkt, Wvt,
                                                  bq, bk, bv, qws, kws, vtg,
                                                  og0, lg, 1, 0x211);
    attn<<<dim3(2048), 256, 0, stream>>>(qws, kws, vtg, Ebf, attnw, og0, og1, lg);
    rescale<<<dim3(32768), 256, 0, stream>>>(attnw, lg);
    gemm_bf16<<<dim3(8, 32, 1), 256, 0, stream>>>(og0, og0, og0, Wfct, Wfct, Wfct,
                                                  bfc, bfc, bfc, out0, out0, out0,
                                                  og1, lg, 2, 0x0);
}

// Round 10
// 260.767 us; speedup vs baseline: 1.8148x; 1.8148x over previous
//
#include <hip/hip_runtime.h>
#include <math.h>

#define L 2048
#define DMODEL 512
#define NH 8
#define DH 64
#define NROWS 4096   // B*L

typedef __attribute__((ext_vector_type(4))) float f32x4;
typedef __attribute__((ext_vector_type(8))) short s16x8;

#define MFMA(a, b, c) __builtin_amdgcn_mfma_f32_16x16x32_bf16(a, b, c, 0, 0, 0)

static __device__ __forceinline__ ushort f2b(float f) {
    union { float f; unsigned u; } v; v.f = f;
    unsigned r = v.u + 0x7FFF + ((v.u >> 16) & 1);
    return (ushort)(r >> 16);
}

// ---------- f32 -> bf16 convert (8 elems/thread) ----------
__global__ __launch_bounds__(256)
void cvt_bf16(const float* __restrict__ in, ushort* __restrict__ out, int n8) {
    int i = blockIdx.x * 256 + threadIdx.x;
    if (i < n8) {
        float4 a = *reinterpret_cast<const float4*>(&in[(size_t)i * 8]);
        float4 b = *reinterpret_cast<const float4*>(&in[(size_t)i * 8 + 4]);
        ushort4 o0; o0.x = f2b(a.x); o0.y = f2b(a.y); o0.z = f2b(a.z); o0.w = f2b(a.w);
        ushort4 o1; o1.x = f2b(b.x); o1.y = f2b(b.y); o1.z = f2b(b.z); o1.w = f2b(b.w);
        *reinterpret_cast<ushort4*>(&out[(size_t)i * 8]) = o0;
        *reinterpret_cast<ushort4*>(&out[(size_t)i * 8 + 4]) = o1;
    }
}

// ---------- W (512x512 f32, row-major [k][n]) -> Wt bf16 [n][k] ----------
__global__ __launch_bounds__(256)
void transpose_w(const float* __restrict__ W0, const float* __restrict__ W1,
                 const float* __restrict__ W2, const float* __restrict__ W3,
                 ushort* __restrict__ T0, ushort* __restrict__ T1,
                 ushort* __restrict__ T2, ushort* __restrict__ T3) {
    const int z = blockIdx.z;
    const float* W = z == 0 ? W0 : (z == 1 ? W1 : (z == 2 ? W2 : W3));
    ushort* T = z == 0 ? T0 : (z == 1 ? T1 : (z == 2 ? T2 : T3));
    __shared__ float Ls[64][65];
    const int tid = threadIdx.x;
    const int k0 = blockIdx.y * 64, n0 = blockIdx.x * 64;
    #pragma unroll
    for (int i = 0; i < 4; ++i) {
        int kk = (tid >> 4) + i * 16, n4 = (tid & 15) * 4;
        float4 v = *reinterpret_cast<const float4*>(&W[(size_t)(k0 + kk) * 512 + n0 + n4]);
        Ls[kk][n4] = v.x; Ls[kk][n4 + 1] = v.y; Ls[kk][n4 + 2] = v.z; Ls[kk][n4 + 3] = v.w;
    }
    __syncthreads();
    #pragma unroll
    for (int i = 0; i < 4; ++i) {
        int nn = (tid >> 4) + i * 16, k4 = (tid & 15) * 4;
        ushort4 o;
        o.x = f2b(Ls[k4 + 0][nn]); o.y = f2b(Ls[k4 + 1][nn]);
        o.z = f2b(Ls[k4 + 2][nn]); o.w = f2b(Ls[k4 + 3][nn]);
        *reinterpret_cast<ushort4*>(&T[(size_t)(n0 + nn) * 512 + k0 + k4]) = o;
    }
}

// ---------- bf16 MFMA GEMM: out = A(4096x512) @ Wt^T + bias ----------
// a_f32: A operand is f32 (converted during staging).
// per-z mode nibble: 0: f32 row-major; 1: bf16 (B,H,L,DH); 2: bf16 (B,H,DH,L).
__global__ __launch_bounds__(256)
void gemm_bf16(const void* __restrict__ A0, const void* __restrict__ A1,
               const void* __restrict__ A2,
               const ushort* __restrict__ W0, const ushort* __restrict__ W1,
               const ushort* __restrict__ W2,
               const float* __restrict__ b0, const float* __restrict__ b1,
               const float* __restrict__ b2,
               void* o0, void* o1, void* o2, int a_f32, int modes) {
    const int z = blockIdx.z;
    const void* A   = z == 0 ? A0 : (z == 1 ? A1 : A2);
    const ushort* Wt = z == 0 ? W0 : (z == 1 ? W1 : W2);
    const float* bias = z == 0 ? b0 : (z == 1 ? b1 : b2);
    void* outp = z == 0 ? o0 : (z == 1 ? o1 : o2);
    const int mode = (modes >> (4 * z)) & 15;

    __shared__ ushort As[128][40];
    __shared__ ushort Bs[64][40];
    const int tid = threadIdx.x;
    const int w = tid >> 6, lane = tid & 63, g = lane >> 4, c = lane & 15;
    const int m0 = blockIdx.y * 128, n0 = blockIdx.x * 64;

    f32x4 acc[2][4];
    #pragma unroll
    for (int rs = 0; rs < 2; ++rs)
        #pragma unroll
        for (int cs = 0; cs < 4; ++cs) acc[rs][cs] = (f32x4){0.f, 0.f, 0.f, 0.f};

    float bsv[4];
    #pragma unroll
    for (int cs = 0; cs < 4; ++cs) bsv[cs] = bias[n0 + 16 * cs + c];

    for (int k0 = 0; k0 < 512; k0 += 32) {
        {
            int row = tid >> 1, kh = (tid & 1) * 16;
            if (a_f32) {
                const float* p = (const float*)A + (size_t)(m0 + row) * 512 + k0 + kh;
                ushort tmp[16];
                #pragma unroll
                for (int q4 = 0; q4 < 4; ++q4) {
                    float4 f = *reinterpret_cast<const float4*>(p + q4 * 4);
                    tmp[q4 * 4 + 0] = f2b(f.x); tmp[q4 * 4 + 1] = f2b(f.y);
                    tmp[q4 * 4 + 2] = f2b(f.z); tmp[q4 * 4 + 3] = f2b(f.w);
                }
                *reinterpret_cast<uint4*>(&As[row][kh]) = *reinterpret_cast<uint4*>(&tmp[0]);
                *reinterpret_cast<uint4*>(&As[row][kh + 8]) = *reinterpret_cast<uint4*>(&tmp[8]);
            } else {
                const ushort* p = (const ushort*)A + (size_t)(m0 + row) * 512 + k0 + kh;
                uint4 x0 = *reinterpret_cast<const uint4*>(p);
                uint4 x1 = *reinterpret_cast<const uint4*>(p + 8);
                *reinterpret_cast<uint4*>(&As[row][kh]) = x0;
                *reinterpret_cast<uint4*>(&As[row][kh + 8]) = x1;
            }
        }
        {
            int n = tid >> 2, kh = (tid & 3) * 8;
            uint4 x = *reinterpret_cast<const uint4*>(&Wt[(size_t)(n0 + n) * 512 + k0 + kh]);
            *reinterpret_cast<uint4*>(&Bs[n][kh]) = x;
        }
        __syncthreads();
        s16x8 af[2], bf[4];
        #pragma unroll
        for (int rs = 0; rs < 2; ++rs)
            af[rs] = *reinterpret_cast<const s16x8*>(&As[32 * w + 16 * rs + c][8 * g]);
        #pragma unroll
        for (int cs = 0; cs < 4; ++cs)
            bf[cs] = *reinterpret_cast<const s16x8*>(&Bs[16 * cs + c][8 * g]);
        #pragma unroll
        for (int rs = 0; rs < 2; ++rs)
            #pragma unroll
            for (int cs = 0; cs < 4; ++cs)
                acc[rs][cs] = MFMA(af[rs], bf[cs], acc[rs][cs]);
        __syncthreads();
    }
    #pragma unroll
    for (int rs = 0; rs < 2; ++rs)
        #pragma unroll
        for (int cs = 0; cs < 4; ++cs)
            #pragma unroll
            for (int r = 0; r < 4; ++r) {
                int row = m0 + 32 * w + 16 * rs + 4 * g + r;
                int n = n0 + 16 * cs + c;
                float v = acc[rs][cs][r] + bsv[cs];
                int bb = row >> 11, l = row & 2047, hh = n >> 6, dh = n & 63;
                if (mode == 0) {
                    ((float*)outp)[(size_t)row * 512 + n] = v;
                } else if (mode == 1) {
                    ((ushort*)outp)[(((size_t)bb * NH + hh) * L + l) * DH + dh] = f2b(v);
                } else {
                    ((ushort*)outp)[(((size_t)bb * NH + hh) * DH + dh) * L + l] = f2b(v);
                }
            }
}

// ---------- fused relative attention: single pass, barrier-free main loop ---
// Grid 1024 = 64 u x 16 bh.  Balanced ib permutation: each CU's 4 resident
// blocks {u, u+16, u+32, u+48} map to ibs {2v, 63-2v, 2v+1, 62-2v} -> exactly
// 130 tile-units per CU regardless of round-robin offset.
// Each WAVE owns 32-col tiles t = w, w+4, ...  Writes unnormalized p = exp(s)
// f32 to attnw via LDS-staged 128B row bursts; accumulates l and O = p @ V.
__global__ __launch_bounds__(256, 4)
void attn(const ushort* __restrict__ qws, const ushort* __restrict__ kws,
          const ushort* __restrict__ vtg, const ushort* __restrict__ Ebf,
          float* __restrict__ attnw, ushort* __restrict__ ows,
          float* __restrict__ linvg) {
    __shared__ float Ored[4][32][68];   // per-wave alias: Ps[32][36] f32 + Pw[32][40] bf16
    __shared__ float lred[4][32];
    __shared__ float linvs[32];

    const int tid = threadIdx.x;
    const int w = tid >> 6, lane = tid & 63, g = lane >> 4, c = lane & 15;
    const int bid = blockIdx.x;
    const int bh = bid & 15;
    const int u = bid >> 4;
    const int qd = u >> 4, v = u & 15;
    const int ib = (qd == 0) ? 2 * v : (qd == 1) ? (63 - 2 * v)
                 : (qd == 2) ? (2 * v + 1) : (62 - 2 * v);
    const int b = bh >> 3, h = bh & 7;
    const int i0 = ib * 32;
    const int nt = ib + 1;                  // 32-col tiles

    const ushort* qb = qws + (size_t)bh * L * DH;
    const ushort* kb = kws + (size_t)bh * L * DH;
    const ushort* vt = vtg + (size_t)bh * DH * L;
    float* ab = attnw + (size_t)bh * L * L;

    float*  Ps = &Ored[w][0][0];                 // [32][36] f32
    ushort* Pw = (ushort*)(Ps + 32 * 36);        // [32][40] bf16

    s16x8 aq[2][2];
    #pragma unroll
    for (int rs = 0; rs < 2; ++rs)
        #pragma unroll
        for (int ks = 0; ks < 2; ++ks)
            aq[rs][ks] = *reinterpret_cast<const s16x8*>(
                qb + (size_t)(i0 + 16 * rs + c) * DH + 32 * ks + 8 * g);

    float lsum[2][4] = {};
    f32x4 O[2][4];
    #pragma unroll
    for (int rs = 0; rs < 2; ++rs)
        #pragma unroll
        for (int cs = 0; cs < 4; ++cs) O[rs][cs] = (f32x4){0.f, 0.f, 0.f, 0.f};

    for (int t = w; t < nt; t += 4) {
        const int j0 = t * 32;
        const int rbase = L - 32 - i0 + j0;   // E row = rbase+s, s = 31+jl-il
        // --- T strip (32x64) via MFMA ---
        f32x4 TT[4][2];
        #pragma unroll
        for (int ct = 0; ct < 4; ++ct) {
            int rg = rbase + 16 * ct + c;
            rg = rg > L - 1 ? L - 1 : rg;     // clamped rows feed masked cols only
            s16x8 be0 = *reinterpret_cast<const s16x8*>(Ebf + (size_t)rg * DH + 8 * g);
            s16x8 be1 = *reinterpret_cast<const s16x8*>(Ebf + (size_t)rg * DH + 32 + 8 * g);
            #pragma unroll
            for (int rs = 0; rs < 2; ++rs) {
                f32x4 x = {0.f, 0.f, 0.f, 0.f};
                x = MFMA(aq[rs][0], be0, x);
                x = MFMA(aq[rs][1], be1, x);
                TT[ct][rs] = x;
            }
        }
        // --- in-wave diagonal gather: rel = T[il][31+jl-il] ---
        float rel[2][2][4];
        #pragma unroll
        for (int r = 0; r < 4; ++r) {
            const int u2 = c - 4 * g - r;
            const int src = (lane & 48) | ((15 + u2) & 15);
            const bool hi = (u2 >= 1);
            #pragma unroll
            for (int rs = 0; rs < 2; ++rs)
                #pragma unroll
                for (int jh = 0; jh < 2; ++jh) {
                    const int b0 = jh - rs + 1;
                    float va = __shfl(TT[b0][rs][r], src);
                    float vb = __shfl(TT[b0 + 1][rs][r], src);
                    rel[rs][jh][r] = hi ? vb : va;
                }
        }
        // --- QK^T, p = exp(s), l accum, Ps/Pw stage ---
        s16x8 bk[2][2];
        #pragma unroll
        for (int jh = 0; jh < 2; ++jh)
            #pragma unroll
            for (int ks = 0; ks < 2; ++ks)
                bk[jh][ks] = *reinterpret_cast<const s16x8*>(
                    kb + (size_t)(j0 + 16 * jh + c) * DH + 32 * ks + 8 * g);
        #pragma unroll
        for (int rs = 0; rs < 2; ++rs)
            #pragma unroll
            for (int jh = 0; jh < 2; ++jh) {
                f32x4 x = {0.f, 0.f, 0.f, 0.f};
                x = MFMA(aq[rs][0], bk[jh][0], x);
                x = MFMA(aq[rs][1], bk[jh][1], x);
                #pragma unroll
                for (int r = 0; r < 4; ++r) {
                    const int il = 16 * rs + 4 * g + r;
                    const int jl = 16 * jh + c;
                    float s = (x[r] + rel[rs][jh][r]) * 0.125f;
                    float p = (j0 + jl <= i0 + il) ? __expf(s) : 0.0f;
                    lsum[rs][r] += p;
                    Ps[il * 36 + jl] = p;
                    Pw[il * 40 + jl] = f2b(p);
                }
            }
        // --- coalesced unnormalized p write: 128B per row (wave-synchronous) ---
        {
            const int row = lane >> 1, cb = (lane & 1) * 16;
            float* dst = &ab[(size_t)(i0 + row) * L + j0 + cb];
            const float* srcp = &Ps[row * 36 + cb];
            #pragma unroll
            for (int e = 0; e < 4; ++e)
                *reinterpret_cast<float4*>(dst + 4 * e) =
                    *reinterpret_cast<const float4*>(srcp + 4 * e);
        }
        // --- PV with unnormalized bf16 P ---
        s16x8 pa[2];
        #pragma unroll
        for (int rs2 = 0; rs2 < 2; ++rs2)
            pa[rs2] = *reinterpret_cast<const s16x8*>(&Pw[(16 * rs2 + c) * 40 + 8 * g]);
        #pragma unroll
        for (int cs = 0; cs < 4; ++cs) {
            s16x8 vtb = *reinterpret_cast<const s16x8*>(
                vt + (size_t)(16 * cs + c) * L + j0 + 8 * g);
            #pragma unroll
            for (int rs2 = 0; rs2 < 2; ++rs2)
                O[rs2][cs] = MFMA(pa[rs2], vtb, O[rs2][cs]);
        }
    }

    // --- l merge ---
    #pragma unroll
    for (int rs = 0; rs < 2; ++rs)
        #pragma unroll
        for (int r = 0; r < 4; ++r) {
            float s = lsum[rs][r];
            s += __shfl_xor(s, 1); s += __shfl_xor(s, 2);
            s += __shfl_xor(s, 4); s += __shfl_xor(s, 8);
            if (c == 0) lred[w][16 * rs + 4 * g + r] = s;
        }
    __syncthreads();
    if (tid < 32) {
        float l = lred[0][tid] + lred[1][tid] + lred[2][tid] + lred[3][tid];
        float inv = 1.0f / l;
        linvs[tid] = inv;
        linvg[(size_t)bh * L + i0 + tid] = inv;
    }
    __syncthreads();                         // Ps/Pw dead; Ored reuse safe

    // --- O merge across waves ---
    #pragma unroll
    for (int rs2 = 0; rs2 < 2; ++rs2)
        #pragma unroll
        for (int cs = 0; cs < 4; ++cs)
            #pragma unroll
            for (int r = 0; r < 4; ++r)
                Ored[w][16 * rs2 + 4 * g + r][16 * cs + c] = O[rs2][cs][r];
    __syncthreads();
    {
        const int i = tid >> 3, d8 = (tid & 7) * 8;
        const float inv = linvs[i];
        ushort o[8];
        #pragma unroll
        for (int e = 0; e < 8; ++e) {
            float a = Ored[0][i][d8 + e] + Ored[1][i][d8 + e]
                    + Ored[2][i][d8 + e] + Ored[3][i][d8 + e];
            o[e] = f2b(a * inv);
        }
        *reinterpret_cast<uint4*>(
            &ows[((size_t)b * L + i0 + i) * DMODEL + h * DH + d8]) =
            *reinterpret_cast<const uint4*>(&o[0]);
    }
}

// ---------- in-place row rescale of attnw + masked-region zero fill ----------
__global__ __launch_bounds__(256)
void rescale(float* __restrict__ attnw, const float* __restrict__ linvg) {
    const int blk = blockIdx.x;
    const int bh = blk >> 11, i = blk & 2047;
    const float inv = linvg[((size_t)bh << 11) + i];
    float* rowp = attnw + (((size_t)bh << 11) + i) * 2048;
    const int c8 = threadIdx.x * 8;
    float4 a, b2;
    if (c8 + 7 <= i) {
        a  = *reinterpret_cast<const float4*>(rowp + c8);
        b2 = *reinterpret_cast<const float4*>(rowp + c8 + 4);
        a.x *= inv; a.y *= inv; a.z *= inv; a.w *= inv;
        b2.x *= inv; b2.y *= inv; b2.z *= inv; b2.w *= inv;
    } else if (c8 <= i) {
        a  = *reinterpret_cast<const float4*>(rowp + c8);
        b2 = *reinterpret_cast<const float4*>(rowp + c8 + 4);
        a.x  = (c8 + 0 <= i) ? a.x  * inv : 0.f;
        a.y  = (c8 + 1 <= i) ? a.y  * inv : 0.f;
        a.z  = (c8 + 2 <= i) ? a.z  * inv : 0.f;
        a.w  = (c8 + 3 <= i) ? a.w  * inv : 0.f;
        b2.x = (c8 + 4 <= i) ? b2.x * inv : 0.f;
        b2.y = (c8 + 5 <= i) ? b2.y * inv : 0.f;
        b2.z = (c8 + 6 <= i) ? b2.z * inv : 0.f;
        b2.w = (c8 + 7 <= i) ? b2.w * inv : 0.f;
    } else {
        a = make_float4(0.f, 0.f, 0.f, 0.f);
        b2 = a;
    }
    *reinterpret_cast<float4*>(rowp + c8) = a;
    *reinterpret_cast<float4*>(rowp + c8 + 4) = b2;
}

extern "C" void kernel_launch(void* const* d_in, const int* in_sizes, int n_in,
                              void* d_out, int out_size, void* d_ws, size_t ws_size,
                              hipStream_t stream) {
    const float* q_in = (const float*)d_in[0];
    const float* k_in = (const float*)d_in[1];
    const float* v_in = (const float*)d_in[2];
    const float* Wq  = (const float*)d_in[4];
    const float* bq  = (const float*)d_in[5];
    const float* Wk  = (const float*)d_in[6];
    const float* bk  = (const float*)d_in[7];
    const float* Wv  = (const float*)d_in[8];
    const float* bv  = (const float*)d_in[9];
    const float* Wfc = (const float*)d_in[10];
    const float* bfc = (const float*)d_in[11];
    const float* E   = (const float*)d_in[12];

    float* out0  = (float*)d_out;                        // (B,L,D) f32
    float* attnw = out0 + (size_t)2 * L * DMODEL;        // (B,H,L,L) f32

    const size_t NA = (size_t)NROWS * DMODEL;            // 2,097,152
    ushort* ws = (ushort*)d_ws;
    ushort* Ebf  = ws;                                   // 131072 us
    ushort* Wqt  = Ebf + (size_t)L * DH;
    ushort* Wkt  = Wqt + 262144;
    ushort* Wvt  = Wkt + 262144;
    ushort* Wfct = Wvt + 262144;
    ushort* qws  = Wfct + 262144;
    ushort* kws  = qws + NA;
    ushort* vtg  = kws + NA;                             // (B,H,DH,L) bf16
    ushort* ows  = vtg + NA;
    float*  linvg = (float*)(ows + NA);                  // (B*H, L) f32

    cvt_bf16<<<dim3(64), 256, 0, stream>>>(E, Ebf, (int)(L * DH / 8));
    transpose_w<<<dim3(8, 8, 4), 256, 0, stream>>>(Wq, Wk, Wv, Wfc, Wqt, Wkt, Wvt, Wfct);
    // q, k -> (B,H,L,DH); v -> transposed (B,H,DH,L)
    gemm_bf16<<<dim3(8, 32, 3), 256, 0, stream>>>(q_in, k_in, v_in, Wqt, Wkt, Wvt,
                                                  bq, bk, bv, qws, kws, vtg,
                                                  1, 0x211);
    attn<<<dim3(1024), 256, 0, stream>>>(qws, kws, vtg, Ebf, attnw, ows, linvg);
    rescale<<<dim3(32768), 256, 0, stream>>>(attnw, linvg);
    gemm_bf16<<<dim3(8, 32, 1), 256, 0, stream>>>(ows, ows, ows, Wfct, Wfct, Wfct,
                                                  bfc, bfc, bfc, out0, out0, out0,
                                                  0, 0x0);
}

// Round 11
// 194.466 us; speedup vs baseline: 2.4335x; 1.3409x over previous
//
#include <hip/hip_runtime.h>
#include <math.h>

#define L 2048
#define DMODEL 512
#define NH 8
#define DH 64
#define NROWS 4096   // B*L

typedef __attribute__((ext_vector_type(4))) float f32x4;
typedef __attribute__((ext_vector_type(8))) short s16x8;

#define MFMA(a, b, c) __builtin_amdgcn_mfma_f32_16x16x32_bf16(a, b, c, 0, 0, 0)

static __device__ __forceinline__ ushort f2b(float f) {
    union { float f; unsigned u; } v; v.f = f;
    unsigned r = v.u + 0x7FFF + ((v.u >> 16) & 1);
    return (ushort)(r >> 16);
}

// ---------- W (512x512 f32) -> Wt bf16 [n][k]; z==4: E f32 -> bf16 ----------
__global__ __launch_bounds__(256)
void transpose_w(const float* __restrict__ W0, const float* __restrict__ W1,
                 const float* __restrict__ W2, const float* __restrict__ W3,
                 ushort* __restrict__ T0, ushort* __restrict__ T1,
                 ushort* __restrict__ T2, ushort* __restrict__ T3,
                 const float* __restrict__ E, ushort* __restrict__ Ebf) {
    const int z = blockIdx.z;
    const int tid = threadIdx.x;
    if (z == 4) {   // E convert: 64 blocks x 256 thr x 8 elems = 131072
        const int i = (blockIdx.y * 8 + blockIdx.x) * 256 + tid;
        float4 a = *reinterpret_cast<const float4*>(&E[(size_t)i * 8]);
        float4 b = *reinterpret_cast<const float4*>(&E[(size_t)i * 8 + 4]);
        ushort4 o0; o0.x = f2b(a.x); o0.y = f2b(a.y); o0.z = f2b(a.z); o0.w = f2b(a.w);
        ushort4 o1; o1.x = f2b(b.x); o1.y = f2b(b.y); o1.z = f2b(b.z); o1.w = f2b(b.w);
        *reinterpret_cast<ushort4*>(&Ebf[(size_t)i * 8]) = o0;
        *reinterpret_cast<ushort4*>(&Ebf[(size_t)i * 8 + 4]) = o1;
        return;
    }
    const float* W = z == 0 ? W0 : (z == 1 ? W1 : (z == 2 ? W2 : W3));
    ushort* T = z == 0 ? T0 : (z == 1 ? T1 : (z == 2 ? T2 : T3));
    __shared__ float Ls[64][65];
    const int k0 = blockIdx.y * 64, n0 = blockIdx.x * 64;
    #pragma unroll
    for (int i = 0; i < 4; ++i) {
        int kk = (tid >> 4) + i * 16, n4 = (tid & 15) * 4;
        float4 v = *reinterpret_cast<const float4*>(&W[(size_t)(k0 + kk) * 512 + n0 + n4]);
        Ls[kk][n4] = v.x; Ls[kk][n4 + 1] = v.y; Ls[kk][n4 + 2] = v.z; Ls[kk][n4 + 3] = v.w;
    }
    __syncthreads();
    #pragma unroll
    for (int i = 0; i < 4; ++i) {
        int nn = (tid >> 4) + i * 16, k4 = (tid & 15) * 4;
        ushort4 o;
        o.x = f2b(Ls[k4 + 0][nn]); o.y = f2b(Ls[k4 + 1][nn]);
        o.z = f2b(Ls[k4 + 2][nn]); o.w = f2b(Ls[k4 + 3][nn]);
        *reinterpret_cast<ushort4*>(&T[(size_t)(n0 + nn) * 512 + k0 + k4]) = o;
    }
}

// ---------- bf16 MFMA GEMM: out = A(4096x512) @ Wt^T + bias ----------
// a_f32: A operand is f32 (converted during staging).
// per-z mode nibble: 0: f32 row-major; 1: bf16 (B,H,L,DH); 2: bf16 (B,H,DH,L).
__global__ __launch_bounds__(256)
void gemm_bf16(const void* __restrict__ A0, const void* __restrict__ A1,
               const void* __restrict__ A2,
               const ushort* __restrict__ W0, const ushort* __restrict__ W1,
               const ushort* __restrict__ W2,
               const float* __restrict__ b0, const float* __restrict__ b1,
               const float* __restrict__ b2,
               void* o0, void* o1, void* o2, int a_f32, int modes) {
    const int z = blockIdx.z;
    const void* A   = z == 0 ? A0 : (z == 1 ? A1 : A2);
    const ushort* Wt = z == 0 ? W0 : (z == 1 ? W1 : W2);
    const float* bias = z == 0 ? b0 : (z == 1 ? b1 : b2);
    void* outp = z == 0 ? o0 : (z == 1 ? o1 : o2);
    const int mode = (modes >> (4 * z)) & 15;

    __shared__ ushort As[128][40];
    __shared__ ushort Bs[64][40];
    const int tid = threadIdx.x;
    const int w = tid >> 6, lane = tid & 63, g = lane >> 4, c = lane & 15;
    const int m0 = blockIdx.y * 128, n0 = blockIdx.x * 64;

    f32x4 acc[2][4];
    #pragma unroll
    for (int rs = 0; rs < 2; ++rs)
        #pragma unroll
        for (int cs = 0; cs < 4; ++cs) acc[rs][cs] = (f32x4){0.f, 0.f, 0.f, 0.f};

    float bsv[4];
    #pragma unroll
    for (int cs = 0; cs < 4; ++cs) bsv[cs] = bias[n0 + 16 * cs + c];

    for (int k0 = 0; k0 < 512; k0 += 32) {
        {
            int row = tid >> 1, kh = (tid & 1) * 16;
            if (a_f32) {
                const float* p = (const float*)A + (size_t)(m0 + row) * 512 + k0 + kh;
                ushort tmp[16];
                #pragma unroll
                for (int q4 = 0; q4 < 4; ++q4) {
                    float4 f = *reinterpret_cast<const float4*>(p + q4 * 4);
                    tmp[q4 * 4 + 0] = f2b(f.x); tmp[q4 * 4 + 1] = f2b(f.y);
                    tmp[q4 * 4 + 2] = f2b(f.z); tmp[q4 * 4 + 3] = f2b(f.w);
                }
                *reinterpret_cast<uint4*>(&As[row][kh]) = *reinterpret_cast<uint4*>(&tmp[0]);
                *reinterpret_cast<uint4*>(&As[row][kh + 8]) = *reinterpret_cast<uint4*>(&tmp[8]);
            } else {
                const ushort* p = (const ushort*)A + (size_t)(m0 + row) * 512 + k0 + kh;
                uint4 x0 = *reinterpret_cast<const uint4*>(p);
                uint4 x1 = *reinterpret_cast<const uint4*>(p + 8);
                *reinterpret_cast<uint4*>(&As[row][kh]) = x0;
                *reinterpret_cast<uint4*>(&As[row][kh + 8]) = x1;
            }
        }
        {
            int n = tid >> 2, kh = (tid & 3) * 8;
            uint4 x = *reinterpret_cast<const uint4*>(&Wt[(size_t)(n0 + n) * 512 + k0 + kh]);
            *reinterpret_cast<uint4*>(&Bs[n][kh]) = x;
        }
        __syncthreads();
        s16x8 af[2], bf[4];
        #pragma unroll
        for (int rs = 0; rs < 2; ++rs)
            af[rs] = *reinterpret_cast<const s16x8*>(&As[32 * w + 16 * rs + c][8 * g]);
        #pragma unroll
        for (int cs = 0; cs < 4; ++cs)
            bf[cs] = *reinterpret_cast<const s16x8*>(&Bs[16 * cs + c][8 * g]);
        #pragma unroll
        for (int rs = 0; rs < 2; ++rs)
            #pragma unroll
            for (int cs = 0; cs < 4; ++cs)
                acc[rs][cs] = MFMA(af[rs], bf[cs], acc[rs][cs]);
        __syncthreads();
    }
    #pragma unroll
    for (int rs = 0; rs < 2; ++rs)
        #pragma unroll
        for (int cs = 0; cs < 4; ++cs)
            #pragma unroll
            for (int r = 0; r < 4; ++r) {
                int row = m0 + 32 * w + 16 * rs + 4 * g + r;
                int n = n0 + 16 * cs + c;
                float v = acc[rs][cs][r] + bsv[cs];
                int bb = row >> 11, l = row & 2047, hh = n >> 6, dh = n & 63;
                if (mode == 0) {
                    ((float*)outp)[(size_t)row * 512 + n] = v;
                } else if (mode == 1) {
                    ((ushort*)outp)[(((size_t)bb * NH + hh) * L + l) * DH + dh] = f2b(v);
                } else {
                    ((ushort*)outp)[(((size_t)bb * NH + hh) * DH + dh) * L + l] = f2b(v);
                }
            }
}

// ---------- fused relative attention: single pass, barrier-free main loop ---
// One wg per (bh, 32-row i-block), heavy-first; within a wg each WAVE
// independently owns 32-col key tiles t = w, w+4, ...  Writes unnormalized
// p = exp(s) (f32) to attnw, accumulates l and O = p @ V; rescale kernel
// applies 1/l to attnw in place.   [R5 champion structure — do not tweak]
__global__ __launch_bounds__(256, 3)
void attn(const ushort* __restrict__ qws, const ushort* __restrict__ kws,
          const ushort* __restrict__ vtg, const ushort* __restrict__ Ebf,
          float* __restrict__ attnw, ushort* __restrict__ ows,
          float* __restrict__ linvg) {
    __shared__ float Ored[4][32][68];       // also aliased as per-wave P scratch
    __shared__ float lred[4][32];
    __shared__ float linvs[32];

    const int tid = threadIdx.x;
    const int w = tid >> 6, lane = tid & 63, g = lane >> 4, c = lane & 15;
    const int bid = blockIdx.x;
    const int bh = bid & 15;
    const int ib = 63 - (bid >> 4);         // heavy-first
    const int b = bh >> 3, h = bh & 7;
    const int i0 = ib * 32;
    const int nt = ib + 1;                  // 32-col tiles

    const ushort* qb = qws + (size_t)bh * L * DH;
    const ushort* kb = kws + (size_t)bh * L * DH;
    const ushort* vt = vtg + (size_t)bh * DH * L;
    float* ab = attnw + (size_t)bh * L * L;

    // per-wave P scratch (bf16 [32][40]) aliased onto Ored[w]
    ushort (*Pw)[40] = reinterpret_cast<ushort(*)[40]>(&Ored[w][0][0]);

    s16x8 aq[2][2];
    #pragma unroll
    for (int rs = 0; rs < 2; ++rs)
        #pragma unroll
        for (int ks = 0; ks < 2; ++ks)
            aq[rs][ks] = *reinterpret_cast<const s16x8*>(
                qb + (size_t)(i0 + 16 * rs + c) * DH + 32 * ks + 8 * g);

    f32x4 O[2][4];
    #pragma unroll
    for (int rs = 0; rs < 2; ++rs)
        #pragma unroll
        for (int cs = 0; cs < 4; ++cs) O[rs][cs] = (f32x4){0.f, 0.f, 0.f, 0.f};
    float lsum[2][4] = {};

    for (int t = w; t < nt; t += 4) {
        const int j0 = t * 32;
        const int rbase = L - 32 - i0 + j0;   // E row = rbase + s, s = 31+jl-il

        // --- T strip: T[il][s] = Q . E^T, s in [0,64) (4 col-tiles) ---
        f32x4 TT[4][2];
        #pragma unroll
        for (int ct = 0; ct < 4; ++ct) {
            s16x8 be[2];
            int rg = rbase + 16 * ct + c;
            rg = rg > L - 1 ? L - 1 : rg;     // clamped rows only feed masked cols
            #pragma unroll
            for (int ks = 0; ks < 2; ++ks)
                be[ks] = *reinterpret_cast<const s16x8*>(
                    Ebf + (size_t)rg * DH + 32 * ks + 8 * g);
            #pragma unroll
            for (int rs = 0; rs < 2; ++rs) {
                f32x4 x = {0.f, 0.f, 0.f, 0.f};
                x = MFMA(aq[rs][0], be[0], x);
                x = MFMA(aq[rs][1], be[1], x);
                TT[ct][rs] = x;
            }
        }
        // --- in-wave diagonal gather: rel[rs][jh][r] = T[il][31+jl-il] ---
        float rel[2][2][4];
        #pragma unroll
        for (int r = 0; r < 4; ++r) {
            const int u = c - 4 * g - r;
            const int src = (lane & 48) | ((15 + u) & 15);
            const bool hi = (u >= 1);
            #pragma unroll
            for (int rs = 0; rs < 2; ++rs)
                #pragma unroll
                for (int jh = 0; jh < 2; ++jh) {
                    const int b0 = jh - rs + 1;
                    float va = __shfl(TT[b0][rs][r], src);
                    float vb = __shfl(TT[b0 + 1][rs][r], src);
                    rel[rs][jh][r] = hi ? vb : va;
                }
        }
        // --- QK^T ---
        f32x4 SK[2][2];
        {
            s16x8 bk[2][2];
            #pragma unroll
            for (int jh = 0; jh < 2; ++jh)
                #pragma unroll
                for (int ks = 0; ks < 2; ++ks)
                    bk[jh][ks] = *reinterpret_cast<const s16x8*>(
                        kb + (size_t)(j0 + 16 * jh + c) * DH + 32 * ks + 8 * g);
            #pragma unroll
            for (int rs = 0; rs < 2; ++rs)
                #pragma unroll
                for (int jh = 0; jh < 2; ++jh) {
                    f32x4 x = {0.f, 0.f, 0.f, 0.f};
                    x = MFMA(aq[rs][0], bk[jh][0], x);
                    x = MFMA(aq[rs][1], bk[jh][1], x);
                    SK[rs][jh] = x;
                }
        }
        // --- p = exp(s), l accumulation, global p write, P scratch ---
        #pragma unroll
        for (int rs = 0; rs < 2; ++rs)
            #pragma unroll
            for (int jh = 0; jh < 2; ++jh)
                #pragma unroll
                for (int r = 0; r < 4; ++r) {
                    const int il = 16 * rs + 4 * g + r;
                    const int jl = 16 * jh + c;
                    float s = (SK[rs][jh][r] + rel[rs][jh][r]) * 0.125f;
                    float p = (j0 + jl <= i0 + il) ? __expf(s) : 0.0f;
                    lsum[rs][r] += p;
                    ab[(size_t)(i0 + il) * L + j0 + jl] = p;
                    Pw[il][jl] = f2b(p);
                }
        // --- PV: O += P @ V  (V^T fragments straight from global) ---
        s16x8 pa[2];
        #pragma unroll
        for (int rs2 = 0; rs2 < 2; ++rs2)
            pa[rs2] = *reinterpret_cast<const s16x8*>(&Pw[16 * rs2 + c][8 * g]);
        #pragma unroll
        for (int cs = 0; cs < 4; ++cs) {
            s16x8 vtb = *reinterpret_cast<const s16x8*>(
                vt + (size_t)(16 * cs + c) * L + j0 + 8 * g);
            #pragma unroll
            for (int rs2 = 0; rs2 < 2; ++rs2)
                O[rs2][cs] = MFMA(pa[rs2], vtb, O[rs2][cs]);
        }
    }

    // --- merges (only barriers in the kernel) ---
    #pragma unroll
    for (int rs = 0; rs < 2; ++rs)
        #pragma unroll
        for (int r = 0; r < 4; ++r) {
            float s = lsum[rs][r];
            s += __shfl_xor(s, 1); s += __shfl_xor(s, 2);
            s += __shfl_xor(s, 4); s += __shfl_xor(s, 8);
            if (c == 0) lred[w][16 * rs + 4 * g + r] = s;
        }
    #pragma unroll
    for (int rs2 = 0; rs2 < 2; ++rs2)
        #pragma unroll
        for (int cs = 0; cs < 4; ++cs)
            #pragma unroll
            for (int r = 0; r < 4; ++r)
                Ored[w][16 * rs2 + 4 * g + r][16 * cs + c] = O[rs2][cs][r];
    __syncthreads();
    if (tid < 32) {
        float l = lred[0][tid] + lred[1][tid] + lred[2][tid] + lred[3][tid];
        float inv = 1.0f / l;
        linvs[tid] = inv;
        linvg[(size_t)bh * L + i0 + tid] = inv;
    }
    __syncthreads();
    {
        const int i = tid >> 3, d8 = (tid & 7) * 8;
        const float inv = linvs[i];
        ushort o[8];
        #pragma unroll
        for (int e = 0; e < 8; ++e) {
            float a = Ored[0][i][d8 + e] + Ored[1][i][d8 + e]
                    + Ored[2][i][d8 + e] + Ored[3][i][d8 + e];
            o[e] = f2b(a * inv);
        }
        *reinterpret_cast<uint4*>(
            &ows[((size_t)b * L + i0 + i) * DMODEL + h * DH + d8]) =
            *reinterpret_cast<const uint4*>(&o[0]);
    }
}

// ---------- in-place row rescale of attnw + masked-region zero fill ----------
__global__ __launch_bounds__(256)
void rescale(float* __restrict__ attnw, const float* __restrict__ linvg) {
    const int blk = blockIdx.x;
    const int bh = blk >> 11, i = blk & 2047;
    const float inv = linvg[(size_t)bh * L + i];
    float* rowp = attnw + ((size_t)bh * L + i) * L;
    const int c8 = threadIdx.x * 8;
    float4 a, b2;
    if (c8 <= i) {
        a  = *reinterpret_cast<const float4*>(rowp + c8);
        b2 = *reinterpret_cast<const float4*>(rowp + c8 + 4);
        a.x  = (c8 + 0 <= i) ? a.x  * inv : 0.f;
        a.y  = (c8 + 1 <= i) ? a.y  * inv : 0.f;
        a.z  = (c8 + 2 <= i) ? a.z  * inv : 0.f;
        a.w  = (c8 + 3 <= i) ? a.w  * inv : 0.f;
        b2.x = (c8 + 4 <= i) ? b2.x * inv : 0.f;
        b2.y = (c8 + 5 <= i) ? b2.y * inv : 0.f;
        b2.z = (c8 + 6 <= i) ? b2.z * inv : 0.f;
        b2.w = (c8 + 7 <= i) ? b2.w * inv : 0.f;
    } else {
        a = make_float4(0.f, 0.f, 0.f, 0.f);
        b2 = a;
    }
    *reinterpret_cast<float4*>(rowp + c8) = a;
    *reinterpret_cast<float4*>(rowp + c8 + 4) = b2;
}

extern "C" void kernel_launch(void* const* d_in, const int* in_sizes, int n_in,
                              void* d_out, int out_size, void* d_ws, size_t ws_size,
                              hipStream_t stream) {
    const float* q_in = (const float*)d_in[0];
    const float* k_in = (const float*)d_in[1];
    const float* v_in = (const float*)d_in[2];
    const float* Wq  = (const float*)d_in[4];
    const float* bq  = (const float*)d_in[5];
    const float* Wk  = (const float*)d_in[6];
    const float* bk  = (const float*)d_in[7];
    const float* Wv  = (const float*)d_in[8];
    const float* bv  = (const float*)d_in[9];
    const float* Wfc = (const float*)d_in[10];
    const float* bfc = (const float*)d_in[11];
    const float* E   = (const float*)d_in[12];

    float* out0  = (float*)d_out;                        // (B,L,D) f32
    float* attnw = out0 + (size_t)2 * L * DMODEL;        // (B,H,L,L) f32

    const size_t NA = (size_t)NROWS * DMODEL;            // 2,097,152
    ushort* ws = (ushort*)d_ws;
    ushort* Ebf  = ws;                                   // 131072 us
    ushort* Wqt  = Ebf + (size_t)L * DH;
    ushort* Wkt  = Wqt + 262144;
    ushort* Wvt  = Wkt + 262144;
    ushort* Wfct = Wvt + 262144;
    ushort* qws  = Wfct + 262144;
    ushort* kws  = qws + NA;
    ushort* vtg  = kws + NA;                             // (B,H,DH,L) bf16
    ushort* ows  = vtg + NA;
    float*  linvg = (float*)(ows + NA);                  // (B*H, L) f32

    transpose_w<<<dim3(8, 8, 5), 256, 0, stream>>>(Wq, Wk, Wv, Wfc,
                                                   Wqt, Wkt, Wvt, Wfct, E, Ebf);
    // q, k -> (B,H,L,DH); v -> transposed (B,H,DH,L)
    gemm_bf16<<<dim3(8, 32, 3), 256, 0, stream>>>(q_in, k_in, v_in, Wqt, Wkt, Wvt,
                                                  bq, bk, bv, qws, kws, vtg,
                                                  1, 0x211);
    attn<<<dim3(1024), 256, 0, stream>>>(qws, kws, vtg, Ebf, attnw, ows, linvg);
    rescale<<<dim3(32768), 256, 0, stream>>>(attnw, linvg);
    gemm_bf16<<<dim3(8, 32, 1), 256, 0, stream>>>(ows, ows, ows, Wfct, Wfct, Wfct,
                                                  bfc, bfc, bfc, out0, out0, out0,
                                                  0, 0x0);
}